// Round 3
// baseline (253.052 us; speedup 1.0000x reference)
//
#include <hip/hip_runtime.h>
#include <hip/hip_cooperative_groups.h>
#include <math.h>

namespace cg = cooperative_groups;

// Problem constants
constexpr int NN = 1024;   // nodes
constexpr int DD = 256;    // embedding dim
constexpr int HH = 128;    // hidden dim
constexpr float BN_EPS = 1e-5f;

// Workspace layout (in floats)
constexpr int OFF_A      = 0;                          // [1024 x 1024] adjacency
constexpr int OFF_AP     = OFF_A + NN * NN;            // [N x H] a + b1
constexpr int OFF_CP     = OFF_AP + NN * HH;           // [N x H] c
constexpr int OFF_Y      = OFF_CP + NN * HH;           // [N x H] X@Wg
constexpr int OFF_DEG    = OFF_Y + NN * HH;            // [N] degree accumulators
constexpr int OFF_STATS  = OFF_DEG + NN;               // [256] colsum, colsumsq
constexpr int OFF_OUTPRE = OFF_STATS + 256;            // [N x H] pre-BN output
constexpr int OFF_P4     = OFF_OUTPRE + NN * HH;       // [8 jchunks][N x H]

// ---------------------------------------------------------------------------
// Single cooperative mega-kernel: 5 phases separated by grid.sync().
// grid 256 x block 256; 48 KB LDS reused across phases.
// ---------------------------------------------------------------------------
__global__ __launch_bounds__(256) void mega(
    const float* __restrict__ X, const float* __restrict__ W1,
    const float* __restrict__ b1, const float* __restrict__ W2,
    const float* __restrict__ b2, const float* __restrict__ Wg,
    const float* __restrict__ bg, const float* __restrict__ gamma,
    const float* __restrict__ beta, float* __restrict__ out,
    float* __restrict__ wsp) {
  cg::grid_group grid = cg::this_grid();
  __shared__ float smem[12288];  // 48 KB, re-purposed per phase

  float* A = wsp + OFF_A;
  float* aP = wsp + OFF_AP;
  float* cP = wsp + OFF_CP;
  float* Y = wsp + OFF_Y;
  float* deg = wsp + OFF_DEG;
  float* stats = wsp + OFF_STATS;
  float* out_pre = wsp + OFF_OUTPRE;
  float* P4 = wsp + OFF_P4;

  const int tid = threadIdx.x;
  const int blk = blockIdx.x;

  // ======================= Phase 1: GEMMs + zero-init ======================
  // aP = X@W1[:D]+b1, cP = X@W1[D:], Y = X@Wg.  192 tasks = 64 rowtiles x 3.
  if (blk < 192) {
    float* xs = smem;          // 16 rows x 256 d  (16 KB)
    float* wb = smem + 4096;   // 64 d x 128 h     (32 KB)
    const int i0 = (blk & 63) * 16;
    const int m = blk >> 6;
    const float* W = (m == 0) ? W1 : (m == 1 ? W1 + DD * HH : Wg);
    const float* Xbase = X + i0 * DD;
#pragma unroll
    for (int v = 0; v < 4; ++v) {
      const int fi = (v * 256 + tid) * 4;
      *(float4*)(xs + fi) = *(const float4*)(Xbase + fi);
    }
    const int tx = tid & 31, ty = tid >> 5;
    float4 acc0 = make_float4(0.f, 0.f, 0.f, 0.f);
    float4 acc1 = make_float4(0.f, 0.f, 0.f, 0.f);
    for (int c = 0; c < 4; ++c) {
      __syncthreads();
      const float* Wbase = W + c * 64 * HH;
#pragma unroll
      for (int v = 0; v < 8; ++v) {
        const int fi = (v * 256 + tid) * 4;
        *(float4*)(wb + fi) = *(const float4*)(Wbase + fi);
      }
      __syncthreads();
      const float* xr0 = xs + (ty * 2) * 256 + c * 64;
      const float* xr1 = xs + (ty * 2 + 1) * 256 + c * 64;
#pragma unroll 4
      for (int d = 0; d < 64; d += 4) {
        const float4 x0 = *(const float4*)(xr0 + d);
        const float4 x1 = *(const float4*)(xr1 + d);
        const float4 w0 = *(const float4*)(wb + (d + 0) * 128 + tx * 4);
        const float4 w1 = *(const float4*)(wb + (d + 1) * 128 + tx * 4);
        const float4 w2 = *(const float4*)(wb + (d + 2) * 128 + tx * 4);
        const float4 w3 = *(const float4*)(wb + (d + 3) * 128 + tx * 4);
        acc0.x = fmaf(x0.x, w0.x, acc0.x); acc0.y = fmaf(x0.x, w0.y, acc0.y);
        acc0.z = fmaf(x0.x, w0.z, acc0.z); acc0.w = fmaf(x0.x, w0.w, acc0.w);
        acc1.x = fmaf(x1.x, w0.x, acc1.x); acc1.y = fmaf(x1.x, w0.y, acc1.y);
        acc1.z = fmaf(x1.x, w0.z, acc1.z); acc1.w = fmaf(x1.x, w0.w, acc1.w);
        acc0.x = fmaf(x0.y, w1.x, acc0.x); acc0.y = fmaf(x0.y, w1.y, acc0.y);
        acc0.z = fmaf(x0.y, w1.z, acc0.z); acc0.w = fmaf(x0.y, w1.w, acc0.w);
        acc1.x = fmaf(x1.y, w1.x, acc1.x); acc1.y = fmaf(x1.y, w1.y, acc1.y);
        acc1.z = fmaf(x1.y, w1.z, acc1.z); acc1.w = fmaf(x1.y, w1.w, acc1.w);
        acc0.x = fmaf(x0.z, w2.x, acc0.x); acc0.y = fmaf(x0.z, w2.y, acc0.y);
        acc0.z = fmaf(x0.z, w2.z, acc0.z); acc0.w = fmaf(x0.z, w2.w, acc0.w);
        acc1.x = fmaf(x1.z, w2.x, acc1.x); acc1.y = fmaf(x1.z, w2.y, acc1.y);
        acc1.z = fmaf(x1.z, w2.z, acc1.z); acc1.w = fmaf(x1.z, w2.w, acc1.w);
        acc0.x = fmaf(x0.w, w3.x, acc0.x); acc0.y = fmaf(x0.w, w3.y, acc0.y);
        acc0.z = fmaf(x0.w, w3.z, acc0.z); acc0.w = fmaf(x0.w, w3.w, acc0.w);
        acc1.x = fmaf(x1.w, w3.x, acc1.x); acc1.y = fmaf(x1.w, w3.y, acc1.y);
        acc1.z = fmaf(x1.w, w3.z, acc1.z); acc1.w = fmaf(x1.w, w3.w, acc1.w);
      }
    }
    float* dst = (m == 0) ? aP : (m == 1 ? cP : Y);
    if (m == 0) {
      const float4 bv = *(const float4*)(b1 + tx * 4);
      acc0.x += bv.x; acc0.y += bv.y; acc0.z += bv.z; acc0.w += bv.w;
      acc1.x += bv.x; acc1.y += bv.y; acc1.z += bv.z; acc1.w += bv.w;
    }
    const int r0 = i0 + ty * 2;
    *(float4*)(dst + r0 * HH + tx * 4) = acc0;
    *(float4*)(dst + (r0 + 1) * HH + tx * 4) = acc1;
  } else if (blk == 192) {
    for (int i = tid; i < NN; i += 256) deg[i] = 0.f;
  } else if (blk == 193) {
    stats[tid] = 0.f;
  }
  grid.sync();

  // ============== Phase 2: pairwise sim -> A, fused degree ================
  // 528 upper-triangle 32x32 tile tasks over 256 blocks.
  {
    float* as = smem;          // 32 x 132
    float* cs = smem + 4224;   // 32 x 132
    float* es = smem + 8448;   // 32 x 33
    const float b2v = b2[0];
    for (int t = blk; t < 528; t += 256) {
      __syncthreads();  // guard smem reuse across iterations
      int tt = t, ti = 0;
      while (tt >= 32 - ti) { tt -= 32 - ti; ++ti; }
      const int tj = ti + tt;
      const int i0 = ti * 32, j0 = tj * 32;
      for (int idx = tid; idx < 32 * HH; idx += 256) {
        const int row = idx >> 7, col = idx & 127;
        as[row * 132 + col] = aP[(i0 + row) * HH + col];
        cs[row * 132 + col] = cP[(j0 + row) * HH + col];
      }
      __syncthreads();
      const int li0 = (tid >> 4) * 2, lj0 = (tid & 15) * 2;
      float s00 = 0.f, s01 = 0.f, s10 = 0.f, s11 = 0.f;
#pragma unroll 8
      for (int h = 0; h < HH; h += 4) {
        const float4 a0 = *(const float4*)(as + li0 * 132 + h);
        const float4 a1 = *(const float4*)(as + (li0 + 1) * 132 + h);
        const float4 c0 = *(const float4*)(cs + lj0 * 132 + h);
        const float4 c1 = *(const float4*)(cs + (lj0 + 1) * 132 + h);
        const float4 w = *(const float4*)(W2 + h);
        s00 += fmaxf(a0.x + c0.x, 0.f) * w.x + fmaxf(a0.y + c0.y, 0.f) * w.y +
               fmaxf(a0.z + c0.z, 0.f) * w.z + fmaxf(a0.w + c0.w, 0.f) * w.w;
        s01 += fmaxf(a0.x + c1.x, 0.f) * w.x + fmaxf(a0.y + c1.y, 0.f) * w.y +
               fmaxf(a0.z + c1.z, 0.f) * w.z + fmaxf(a0.w + c1.w, 0.f) * w.w;
        s10 += fmaxf(a1.x + c0.x, 0.f) * w.x + fmaxf(a1.y + c0.y, 0.f) * w.y +
               fmaxf(a1.z + c0.z, 0.f) * w.z + fmaxf(a1.w + c0.w, 0.f) * w.w;
        s11 += fmaxf(a1.x + c1.x, 0.f) * w.x + fmaxf(a1.y + c1.y, 0.f) * w.y +
               fmaxf(a1.z + c1.z, 0.f) * w.z + fmaxf(a1.w + c1.w, 0.f) * w.w;
      }
      auto edge = [b2v](float s) {
        s += b2v;
        return s > 0.f ? 1.f / (1.f + __expf(-s)) : 0.f;  // sigmoid>0.5 <=> s>0
      };
      es[(li0 + 0) * 33 + lj0 + 0] = edge(s00);
      es[(li0 + 0) * 33 + lj0 + 1] = edge(s01);
      es[(li0 + 1) * 33 + lj0 + 0] = edge(s10);
      es[(li0 + 1) * 33 + lj0 + 1] = edge(s11);
      __syncthreads();
      if (ti == tj) {
        // Finalize diagonal tile in-place: diag=1, symmetric from upper part.
        float f[2][2];
#pragma unroll
        for (int r = 0; r < 2; ++r)
#pragma unroll
          for (int c = 0; c < 2; ++c) {
            const int li = li0 + r, lj = lj0 + c;
            f[r][c] = (li == lj) ? 1.f
                                 : (li < lj ? es[li * 33 + lj] : es[lj * 33 + li]);
          }
        __syncthreads();
        es[(li0 + 0) * 33 + lj0 + 0] = f[0][0];
        es[(li0 + 0) * 33 + lj0 + 1] = f[0][1];
        es[(li0 + 1) * 33 + lj0 + 0] = f[1][0];
        es[(li0 + 1) * 33 + lj0 + 1] = f[1][1];
        __syncthreads();
      }
      // Fused degree: rows of es -> deg[i0+..]; cols -> deg[j0+..] (off-diag).
      if (tid < 32) {
        float s = 0.f;
#pragma unroll
        for (int c = 0; c < 32; ++c) s += es[tid * 33 + c];
        atomicAdd(deg + i0 + tid, s);
      } else if (tid < 64 && ti != tj) {
        const int c = tid - 32;
        float s = 0.f;
#pragma unroll
        for (int r = 0; r < 32; ++r) s += es[r * 33 + c];
        atomicAdd(deg + j0 + c, s);
      }
      // Write A (and mirror for off-diagonal tiles), coalesced rows.
#pragma unroll
      for (int r = 0; r < 2; ++r)
#pragma unroll
        for (int c = 0; c < 2; ++c) {
          const int li = li0 + r, lj = lj0 + c;
          A[(i0 + li) * NN + j0 + lj] = es[li * 33 + lj];
          if (ti != tj) A[(j0 + li) * NN + i0 + lj] = es[lj * 33 + li];
        }
    }
  }
  grid.sync();

  // ========== Phase 3: P4[bc] = A[:,jc:jc+128] @ (dis_j * Y) ==============
  // Exactly 256 tasks = 32 rowtiles x 8 jchunks; dis_j = rsqrt(deg[j]) inline.
  {
    float* At = smem;          // 128 x 36 (transposed A tile)
    float* ys = smem + 4608;   // 32 x 128
    const int i0 = (blk >> 3) * 32;
    const int jc = (blk & 7) * 128;
    for (int idx = tid; idx < 32 * 128; idx += 256) {
      const int col = idx & 127, row = idx >> 7;
      At[col * 36 + row] = A[(i0 + row) * NN + jc + col];
    }
    const int tx = tid & 31, ty = tid >> 5;
    float4 acc[4];
#pragma unroll
    for (int r = 0; r < 4; ++r) acc[r] = make_float4(0.f, 0.f, 0.f, 0.f);
    for (int s = 0; s < 4; ++s) {
      __syncthreads();
#pragma unroll
      for (int v = 0; v < 4; ++v) {
        const int fi = (v * 256 + tid) * 4;
        const int r = fi >> 7, col = fi & 127;
        const int j = jc + s * 32 + r;
        float4 tv = *(const float4*)(Y + j * HH + col);
        const float dv = rsqrtf(deg[j]);
        tv.x *= dv; tv.y *= dv; tv.z *= dv; tv.w *= dv;
        *(float4*)(ys + fi) = tv;
      }
      __syncthreads();
#pragma unroll 8
      for (int jj = 0; jj < 32; ++jj) {
        const float4 av = *(const float4*)(At + (s * 32 + jj) * 36 + ty * 4);
        const float4 yv = *(const float4*)(ys + jj * 128 + tx * 4);
        acc[0].x = fmaf(av.x, yv.x, acc[0].x); acc[0].y = fmaf(av.x, yv.y, acc[0].y);
        acc[0].z = fmaf(av.x, yv.z, acc[0].z); acc[0].w = fmaf(av.x, yv.w, acc[0].w);
        acc[1].x = fmaf(av.y, yv.x, acc[1].x); acc[1].y = fmaf(av.y, yv.y, acc[1].y);
        acc[1].z = fmaf(av.y, yv.z, acc[1].z); acc[1].w = fmaf(av.y, yv.w, acc[1].w);
        acc[2].x = fmaf(av.z, yv.x, acc[2].x); acc[2].y = fmaf(av.z, yv.y, acc[2].y);
        acc[2].z = fmaf(av.z, yv.z, acc[2].z); acc[2].w = fmaf(av.z, yv.w, acc[2].w);
        acc[3].x = fmaf(av.w, yv.x, acc[3].x); acc[3].y = fmaf(av.w, yv.y, acc[3].y);
        acc[3].z = fmaf(av.w, yv.z, acc[3].z); acc[3].w = fmaf(av.w, yv.w, acc[3].w);
      }
    }
    const int bc = blk & 7;
#pragma unroll
    for (int r = 0; r < 4; ++r) {
      const int i = i0 + ty * 4 + r;
      *(float4*)(P4 + bc * (NN * HH) + i * HH + tx * 4) = acc[r];
    }
  }
  grid.sync();

  // ===== Phase 4: reduce P4, * dis_i, +bg -> out_pre; BN stats atomics =====
  {
    const int h = tid & 127, rg = tid >> 7;
    const int i0 = blk * 4;  // 256 blocks x 4 rows = 1024 rows
    const float bgv = bg[h];
    float ls = 0.f, lq = 0.f;
#pragma unroll
    for (int r = rg; r < 4; r += 2) {
      const int i = i0 + r;
      float v = 0.f;
#pragma unroll
      for (int s = 0; s < 8; ++s) v += P4[s * (NN * HH) + i * HH + h];
      v = v * rsqrtf(deg[i]) + bgv;
      out_pre[i * HH + h] = v;
      ls += v;
      lq += v * v;
    }
    float* sm1 = smem;        // 256
    float* sm2 = smem + 256;  // 256
    sm1[rg * 128 + h] = ls;
    sm2[rg * 128 + h] = lq;
    __syncthreads();
    if (rg == 0) {
      atomicAdd(&stats[h], sm1[h] + sm1[128 + h]);
      atomicAdd(&stats[128 + h], sm2[h] + sm2[128 + h]);
    }
  }
  grid.sync();

  // ================= Phase 5: BatchNorm + ReLU -> d_out ===================
  {
#pragma unroll
    for (int k = 0; k < 2; ++k) {
      const int idx = blk * 512 + k * 256 + tid;
      const int h = idx & 127;
      const float mean = stats[h] * (1.f / NN);
      const float var = stats[128 + h] * (1.f / NN) - mean * mean;
      float v = (out_pre[idx] - mean) * rsqrtf(var + BN_EPS);
      v = gamma[h] * v + beta[h];
      out[idx] = fmaxf(v, 0.f);
    }
  }
}

// ---------------------------------------------------------------------------
extern "C" void kernel_launch(void* const* d_in, const int* in_sizes, int n_in,
                              void* d_out, int out_size, void* d_ws,
                              size_t ws_size, hipStream_t stream) {
  const float* X = (const float*)d_in[0];
  const float* W1 = (const float*)d_in[1];
  const float* b1 = (const float*)d_in[2];
  const float* W2 = (const float*)d_in[3];
  const float* b2 = (const float*)d_in[4];
  const float* Wg = (const float*)d_in[5];
  const float* bg = (const float*)d_in[6];
  const float* gamma = (const float*)d_in[7];
  const float* beta = (const float*)d_in[8];
  float* out = (float*)d_out;
  float* wsp = (float*)d_ws;

  void* args[] = {(void*)&X,  (void*)&W1,    (void*)&b1,   (void*)&W2,
                  (void*)&b2, (void*)&Wg,    (void*)&bg,   (void*)&gamma,
                  (void*)&beta, (void*)&out, (void*)&wsp};
  hipLaunchCooperativeKernel((const void*)mega, dim3(256), dim3(256), args, 0,
                             stream);
}

// Round 4
// 127.886 us; speedup vs baseline: 1.9787x; 1.9787x over previous
//
#include <hip/hip_runtime.h>
#include <math.h>

// Problem constants
constexpr int NN = 1024;   // nodes
constexpr int DD = 256;    // embedding dim
constexpr int HH = 128;    // hidden dim
constexpr float BN_EPS = 1e-5f;

// Workspace layout (in floats)
constexpr int OFF_A      = 0;                          // [1024 x 1024] adjacency
constexpr int OFF_AP     = OFF_A + NN * NN;            // [N x H] a + b1
constexpr int OFF_CP     = OFF_AP + NN * HH;           // [N x H] c
constexpr int OFF_Y      = OFF_CP + NN * HH;           // [N x H] X@Wg
constexpr int OFF_DEG    = OFF_Y + NN * HH;            // [N] degree accumulators
constexpr int OFF_STATS  = OFF_DEG + NN;               // [256] colsum, colsumsq
constexpr int OFF_OUTPRE = OFF_STATS + 256;            // [N x H] pre-BN output

// ---------------------------------------------------------------------------
// K1: fused GEMMs  aP = X@W1[:D]+b1, cP = X@W1[D:], Y = X@Wg.
// grid 194: blocks 0-191 = 64 rowtiles x 3 matrices; 192/193 zero deg/stats.
// ---------------------------------------------------------------------------
__global__ __launch_bounds__(256) void k1_gemm(
    const float* __restrict__ X, const float* __restrict__ W1,
    const float* __restrict__ Wg, const float* __restrict__ b1,
    float* __restrict__ aP, float* __restrict__ cP, float* __restrict__ Y,
    float* __restrict__ deg, float* __restrict__ stats) {
  const int tid = threadIdx.x;
  const int blk = blockIdx.x;
  if (blk >= 192) {
    if (blk == 192) {
      for (int i = tid; i < NN; i += 256) deg[i] = 0.f;
    } else {
      stats[tid] = 0.f;
    }
    return;
  }
  __shared__ float xs[16 * 256];   // 16 KB, [row][d]
  __shared__ float ws[64 * 128];   // 32 KB, [d][h]
  const int i0 = (blk & 63) * 16;
  const int m = blk >> 6;
  const float* W = (m == 0) ? W1 : (m == 1 ? W1 + DD * HH : Wg);
  const float* Xbase = X + i0 * DD;  // contiguous 16 KB
#pragma unroll
  for (int v = 0; v < 4; ++v) {
    const int fi = (v * 256 + tid) * 4;
    *(float4*)(xs + fi) = *(const float4*)(Xbase + fi);
  }
  const int tx = tid & 31, ty = tid >> 5;  // cols tx*4..+3, rows ty*2..+1
  float4 acc0 = make_float4(0.f, 0.f, 0.f, 0.f);
  float4 acc1 = make_float4(0.f, 0.f, 0.f, 0.f);
  for (int c = 0; c < 4; ++c) {
    __syncthreads();
    const float* Wbase = W + c * 64 * HH;  // contiguous 32 KB chunk
#pragma unroll
    for (int v = 0; v < 8; ++v) {
      const int fi = (v * 256 + tid) * 4;
      *(float4*)(ws + fi) = *(const float4*)(Wbase + fi);
    }
    __syncthreads();
    const float* xr0 = xs + (ty * 2) * 256 + c * 64;
    const float* xr1 = xs + (ty * 2 + 1) * 256 + c * 64;
#pragma unroll 4
    for (int d = 0; d < 64; d += 4) {
      const float4 x0 = *(const float4*)(xr0 + d);
      const float4 x1 = *(const float4*)(xr1 + d);
      const float4 w0 = *(const float4*)(ws + (d + 0) * 128 + tx * 4);
      const float4 w1 = *(const float4*)(ws + (d + 1) * 128 + tx * 4);
      const float4 w2 = *(const float4*)(ws + (d + 2) * 128 + tx * 4);
      const float4 w3 = *(const float4*)(ws + (d + 3) * 128 + tx * 4);
      acc0.x = fmaf(x0.x, w0.x, acc0.x); acc0.y = fmaf(x0.x, w0.y, acc0.y);
      acc0.z = fmaf(x0.x, w0.z, acc0.z); acc0.w = fmaf(x0.x, w0.w, acc0.w);
      acc1.x = fmaf(x1.x, w0.x, acc1.x); acc1.y = fmaf(x1.x, w0.y, acc1.y);
      acc1.z = fmaf(x1.x, w0.z, acc1.z); acc1.w = fmaf(x1.x, w0.w, acc1.w);
      acc0.x = fmaf(x0.y, w1.x, acc0.x); acc0.y = fmaf(x0.y, w1.y, acc0.y);
      acc0.z = fmaf(x0.y, w1.z, acc0.z); acc0.w = fmaf(x0.y, w1.w, acc0.w);
      acc1.x = fmaf(x1.y, w1.x, acc1.x); acc1.y = fmaf(x1.y, w1.y, acc1.y);
      acc1.z = fmaf(x1.y, w1.z, acc1.z); acc1.w = fmaf(x1.y, w1.w, acc1.w);
      acc0.x = fmaf(x0.z, w2.x, acc0.x); acc0.y = fmaf(x0.z, w2.y, acc0.y);
      acc0.z = fmaf(x0.z, w2.z, acc0.z); acc0.w = fmaf(x0.z, w2.w, acc0.w);
      acc1.x = fmaf(x1.z, w2.x, acc1.x); acc1.y = fmaf(x1.z, w2.y, acc1.y);
      acc1.z = fmaf(x1.z, w2.z, acc1.z); acc1.w = fmaf(x1.z, w2.w, acc1.w);
      acc0.x = fmaf(x0.w, w3.x, acc0.x); acc0.y = fmaf(x0.w, w3.y, acc0.y);
      acc0.z = fmaf(x0.w, w3.z, acc0.z); acc0.w = fmaf(x0.w, w3.w, acc0.w);
      acc1.x = fmaf(x1.w, w3.x, acc1.x); acc1.y = fmaf(x1.w, w3.y, acc1.y);
      acc1.z = fmaf(x1.w, w3.z, acc1.z); acc1.w = fmaf(x1.w, w3.w, acc1.w);
    }
  }
  float* dst = (m == 0) ? aP : (m == 1 ? cP : Y);
  if (m == 0) {
    const float4 bv = *(const float4*)(b1 + tx * 4);
    acc0.x += bv.x; acc0.y += bv.y; acc0.z += bv.z; acc0.w += bv.w;
    acc1.x += bv.x; acc1.y += bv.y; acc1.z += bv.z; acc1.w += bv.w;
  }
  const int r0 = i0 + ty * 2;
  *(float4*)(dst + r0 * HH + tx * 4) = acc0;
  *(float4*)(dst + (r0 + 1) * HH + tx * 4) = acc1;
}

// ---------------------------------------------------------------------------
// K2: pairwise sim -> symmetric A (diag=1) with FUSED degree accumulation.
// grid 528 = linearized upper-triangle 32x32 tiles; block 256, 2x2 per thread.
// ---------------------------------------------------------------------------
__global__ __launch_bounds__(256) void k2_pairwise(
    const float* __restrict__ aP, const float* __restrict__ cP,
    const float* __restrict__ W2, const float* __restrict__ b2,
    float* __restrict__ A, float* __restrict__ deg) {
  __shared__ float as[32 * 132];
  __shared__ float cs[32 * 132];
  __shared__ float es[32 * 33];
  __shared__ float ws2[128];
  const int tid = threadIdx.x;
  // Linear tile id -> (ti, tj), ti <= tj.
  int tt = blockIdx.x, ti = 0;
  while (tt >= 32 - ti) { tt -= 32 - ti; ++ti; }
  const int tj = ti + tt;
  const int i0 = ti * 32, j0 = tj * 32;
  if (tid < 32) *(float4*)(ws2 + tid * 4) = *(const float4*)(W2 + tid * 4);
  for (int idx = tid; idx < 32 * HH; idx += 256) {
    const int row = idx >> 7, col = idx & 127;
    as[row * 132 + col] = aP[(i0 + row) * HH + col];
    cs[row * 132 + col] = cP[(j0 + row) * HH + col];
  }
  __syncthreads();
  const int li0 = (tid >> 4) * 2, lj0 = (tid & 15) * 2;
  float s00 = 0.f, s01 = 0.f, s10 = 0.f, s11 = 0.f;
#pragma unroll 8
  for (int h = 0; h < HH; h += 4) {
    const float4 a0 = *(const float4*)(as + li0 * 132 + h);
    const float4 a1 = *(const float4*)(as + (li0 + 1) * 132 + h);
    const float4 c0 = *(const float4*)(cs + lj0 * 132 + h);
    const float4 c1 = *(const float4*)(cs + (lj0 + 1) * 132 + h);
    const float4 w = *(const float4*)(ws2 + h);
    s00 += fmaxf(a0.x + c0.x, 0.f) * w.x + fmaxf(a0.y + c0.y, 0.f) * w.y +
           fmaxf(a0.z + c0.z, 0.f) * w.z + fmaxf(a0.w + c0.w, 0.f) * w.w;
    s01 += fmaxf(a0.x + c1.x, 0.f) * w.x + fmaxf(a0.y + c1.y, 0.f) * w.y +
           fmaxf(a0.z + c1.z, 0.f) * w.z + fmaxf(a0.w + c1.w, 0.f) * w.w;
    s10 += fmaxf(a1.x + c0.x, 0.f) * w.x + fmaxf(a1.y + c0.y, 0.f) * w.y +
           fmaxf(a1.z + c0.z, 0.f) * w.z + fmaxf(a1.w + c0.w, 0.f) * w.w;
    s11 += fmaxf(a1.x + c1.x, 0.f) * w.x + fmaxf(a1.y + c1.y, 0.f) * w.y +
           fmaxf(a1.z + c1.z, 0.f) * w.z + fmaxf(a1.w + c1.w, 0.f) * w.w;
  }
  const float b2v = b2[0];
  auto edge = [b2v](float s) {
    s += b2v;
    return s > 0.f ? 1.f / (1.f + __expf(-s)) : 0.f;  // sigmoid>0.5 <=> s>0
  };
  es[(li0 + 0) * 33 + lj0 + 0] = edge(s00);
  es[(li0 + 0) * 33 + lj0 + 1] = edge(s01);
  es[(li0 + 1) * 33 + lj0 + 0] = edge(s10);
  es[(li0 + 1) * 33 + lj0 + 1] = edge(s11);
  __syncthreads();
  if (ti == tj) {  // finalize diagonal tile: diag=1, mirror upper into lower
    float f[2][2];
#pragma unroll
    for (int r = 0; r < 2; ++r)
#pragma unroll
      for (int c = 0; c < 2; ++c) {
        const int li = li0 + r, lj = lj0 + c;
        f[r][c] =
            (li == lj) ? 1.f : (li < lj ? es[li * 33 + lj] : es[lj * 33 + li]);
      }
    __syncthreads();
    es[(li0 + 0) * 33 + lj0 + 0] = f[0][0];
    es[(li0 + 0) * 33 + lj0 + 1] = f[0][1];
    es[(li0 + 1) * 33 + lj0 + 0] = f[1][0];
    es[(li0 + 1) * 33 + lj0 + 1] = f[1][1];
    __syncthreads();
  }
  // Fused degree: row sums -> deg[i0+..]; col sums -> deg[j0+..] (off-diag).
  if (tid < 32) {
    float s = 0.f;
#pragma unroll
    for (int c = 0; c < 32; ++c) s += es[tid * 33 + c];
    atomicAdd(deg + i0 + tid, s);
  } else if (tid < 64 && ti != tj) {
    const int c = tid - 32;
    float s = 0.f;
#pragma unroll
    for (int r = 0; r < 32; ++r) s += es[r * 33 + c];
    atomicAdd(deg + j0 + c, s);
  }
  // Write A (+ mirror for off-diagonal), rows coalesced.
#pragma unroll
  for (int r = 0; r < 2; ++r)
#pragma unroll
    for (int c = 0; c < 2; ++c) {
      const int li = li0 + r, lj = lj0 + c;
      A[(i0 + li) * NN + j0 + lj] = es[li * 33 + lj];
      if (ti != tj) A[(j0 + li) * NN + i0 + lj] = es[lj * 33 + li];
    }
}

// ---------------------------------------------------------------------------
// K3: out_pre = diag(dis) A diag(dis) Y + bg, fused BN-stats atomics.
// grid 256 blocks x 4 rows; A rows + rsqrt(deg) staged in LDS, Y from L2.
// ---------------------------------------------------------------------------
__global__ __launch_bounds__(256) void k3_spmm(
    const float* __restrict__ A, const float* __restrict__ Y,
    const float* __restrict__ deg, const float* __restrict__ bg,
    float* __restrict__ out_pre, float* __restrict__ stats) {
  __shared__ float As[4 * 1024];   // 16 KB: 4 A rows
  __shared__ float disl[1024];     // 4 KB: rsqrt(deg) for all j
  __shared__ float sred[512];
  const int tid = threadIdx.x;
  const int i0 = blockIdx.x * 4;
  const float* Ab = A + i0 * NN;   // contiguous 16 KB
#pragma unroll
  for (int v = 0; v < 4; ++v) {
    const int fi = (v * 256 + tid) * 4;
    *(float4*)(As + fi) = *(const float4*)(Ab + fi);
  }
  {
    const float4 dv = *(const float4*)(deg + tid * 4);
    float4 r;
    r.x = rsqrtf(dv.x); r.y = rsqrtf(dv.y); r.z = rsqrtf(dv.z); r.w = rsqrtf(dv.w);
    *(float4*)(disl + tid * 4) = r;
  }
  __syncthreads();
  const int h = tid & 127, rg = tid >> 7;  // rows rg*2, rg*2+1
  float acc0 = 0.f, acc1 = 0.f;
  const float* Yh = Y + h;
  const float* Ar0 = As + (rg * 2) * 1024;
  const float* Ar1 = As + (rg * 2 + 1) * 1024;
#pragma unroll 4
  for (int j = 0; j < 1024; j += 4) {
    const float4 dv = *(const float4*)(disl + j);
    const float y0 = Yh[(j + 0) * HH] * dv.x;
    const float y1 = Yh[(j + 1) * HH] * dv.y;
    const float y2 = Yh[(j + 2) * HH] * dv.z;
    const float y3 = Yh[(j + 3) * HH] * dv.w;
    const float4 a0 = *(const float4*)(Ar0 + j);
    const float4 a1 = *(const float4*)(Ar1 + j);
    acc0 = fmaf(a0.x, y0, acc0); acc0 = fmaf(a0.y, y1, acc0);
    acc0 = fmaf(a0.z, y2, acc0); acc0 = fmaf(a0.w, y3, acc0);
    acc1 = fmaf(a1.x, y0, acc1); acc1 = fmaf(a1.y, y1, acc1);
    acc1 = fmaf(a1.z, y2, acc1); acc1 = fmaf(a1.w, y3, acc1);
  }
  const float bgv = bg[h];
  const float v0 = acc0 * disl[i0 + rg * 2] + bgv;
  const float v1 = acc1 * disl[i0 + rg * 2 + 1] + bgv;
  out_pre[(i0 + rg * 2) * HH + h] = v0;
  out_pre[(i0 + rg * 2 + 1) * HH + h] = v1;
  sred[rg * 128 + h] = v0 + v1;
  __syncthreads();
  sred[256 + rg * 128 + h] = v0 * v0 + v1 * v1;
  __syncthreads();
  if (rg == 0) {
    atomicAdd(&stats[h], sred[h] + sred[128 + h]);
    atomicAdd(&stats[128 + h], sred[256 + h] + sred[384 + h]);
  }
}

// ---------------------------------------------------------------------------
// K4: BatchNorm (batch stats, biased var) + ReLU -> d_out. grid 512, blk 256
// ---------------------------------------------------------------------------
__global__ __launch_bounds__(256) void k4_bn(
    const float* __restrict__ out_pre, const float* __restrict__ stats,
    const float* __restrict__ gamma, const float* __restrict__ beta,
    float* __restrict__ out) {
  const int idx = blockIdx.x * 256 + threadIdx.x;
  const int h = idx & 127;
  const float mean = stats[h] * (1.f / NN);
  const float var = stats[128 + h] * (1.f / NN) - mean * mean;
  float v = (out_pre[idx] - mean) * rsqrtf(var + BN_EPS);
  v = gamma[h] * v + beta[h];
  out[idx] = fmaxf(v, 0.f);
}

// ---------------------------------------------------------------------------
extern "C" void kernel_launch(void* const* d_in, const int* in_sizes, int n_in,
                              void* d_out, int out_size, void* d_ws,
                              size_t ws_size, hipStream_t stream) {
  const float* X = (const float*)d_in[0];
  const float* W1 = (const float*)d_in[1];
  const float* b1 = (const float*)d_in[2];
  const float* W2 = (const float*)d_in[3];
  const float* b2 = (const float*)d_in[4];
  const float* Wg = (const float*)d_in[5];
  const float* bg = (const float*)d_in[6];
  const float* gamma = (const float*)d_in[7];
  const float* beta = (const float*)d_in[8];
  float* out = (float*)d_out;

  float* w = (float*)d_ws;
  float* A = w + OFF_A;
  float* aP = w + OFF_AP;
  float* cP = w + OFF_CP;
  float* Y = w + OFF_Y;
  float* deg = w + OFF_DEG;
  float* stats = w + OFF_STATS;
  float* out_pre = w + OFF_OUTPRE;

  k1_gemm<<<dim3(194), 256, 0, stream>>>(X, W1, Wg, b1, aP, cP, Y, deg, stats);
  k2_pairwise<<<dim3(528), 256, 0, stream>>>(aP, cP, W2, b2, A, deg);
  k3_spmm<<<dim3(256), 256, 0, stream>>>(A, Y, deg, bg, out_pre, stats);
  k4_bn<<<dim3(512), 256, 0, stream>>>(out_pre, stats, gamma, beta, out);
}

// Round 5
// 117.453 us; speedup vs baseline: 2.1545x; 1.0888x over previous
//
#include <hip/hip_runtime.h>
#include <math.h>

// Problem constants
constexpr int NN = 1024;   // nodes
constexpr int DD = 256;    // embedding dim
constexpr int HH = 128;    // hidden dim
constexpr float BN_EPS = 1e-5f;

// Workspace layout (in floats)
constexpr int OFF_A      = 0;                          // [1024 x 1024] adjacency
constexpr int OFF_AP     = OFF_A + NN * NN;            // [N x H] a + b1
constexpr int OFF_CP     = OFF_AP + NN * HH;           // [N x H] c
constexpr int OFF_Y      = OFF_CP + NN * HH;           // [N x H] X@Wg
constexpr int OFF_DEG    = OFF_Y + NN * HH;            // [N] degree accumulators
constexpr int OFF_STATS  = OFF_DEG + NN;               // [256] colsum, colsumsq
constexpr int OFF_OUTPRE = OFF_STATS + 256;            // [N x H] pre-BN output

// ---------------------------------------------------------------------------
// K1: fused GEMMs  aP = X@W1[:D]+b1, cP = X@W1[D:], Y = X@Wg.
// grid 194: blocks 0-191 = 64 rowtiles x 3 matrices; 192/193 zero deg/stats.
// ---------------------------------------------------------------------------
__global__ __launch_bounds__(256) void k1_gemm(
    const float* __restrict__ X, const float* __restrict__ W1,
    const float* __restrict__ Wg, const float* __restrict__ b1,
    float* __restrict__ aP, float* __restrict__ cP, float* __restrict__ Y,
    float* __restrict__ deg, float* __restrict__ stats) {
  const int tid = threadIdx.x;
  const int blk = blockIdx.x;
  if (blk >= 192) {
    if (blk == 192) {
      for (int i = tid; i < NN; i += 256) deg[i] = 0.f;
    } else {
      stats[tid] = 0.f;
    }
    return;
  }
  __shared__ float xs[16 * 256];   // 16 KB, [row][d]
  __shared__ float ws[64 * 128];   // 32 KB, [d][h]
  const int i0 = (blk & 63) * 16;
  const int m = blk >> 6;
  const float* W = (m == 0) ? W1 : (m == 1 ? W1 + DD * HH : Wg);
  const float* Xbase = X + i0 * DD;  // contiguous 16 KB
#pragma unroll
  for (int v = 0; v < 4; ++v) {
    const int fi = (v * 256 + tid) * 4;
    *(float4*)(xs + fi) = *(const float4*)(Xbase + fi);
  }
  const int tx = tid & 31, ty = tid >> 5;  // cols tx*4..+3, rows ty*2..+1
  float4 acc0 = make_float4(0.f, 0.f, 0.f, 0.f);
  float4 acc1 = make_float4(0.f, 0.f, 0.f, 0.f);
  for (int c = 0; c < 4; ++c) {
    __syncthreads();
    const float* Wbase = W + c * 64 * HH;  // contiguous 32 KB chunk
#pragma unroll
    for (int v = 0; v < 8; ++v) {
      const int fi = (v * 256 + tid) * 4;
      *(float4*)(ws + fi) = *(const float4*)(Wbase + fi);
    }
    __syncthreads();
    const float* xr0 = xs + (ty * 2) * 256 + c * 64;
    const float* xr1 = xs + (ty * 2 + 1) * 256 + c * 64;
#pragma unroll 4
    for (int d = 0; d < 64; d += 4) {
      const float4 x0 = *(const float4*)(xr0 + d);
      const float4 x1 = *(const float4*)(xr1 + d);
      const float4 w0 = *(const float4*)(ws + (d + 0) * 128 + tx * 4);
      const float4 w1 = *(const float4*)(ws + (d + 1) * 128 + tx * 4);
      const float4 w2 = *(const float4*)(ws + (d + 2) * 128 + tx * 4);
      const float4 w3 = *(const float4*)(ws + (d + 3) * 128 + tx * 4);
      acc0.x = fmaf(x0.x, w0.x, acc0.x); acc0.y = fmaf(x0.x, w0.y, acc0.y);
      acc0.z = fmaf(x0.x, w0.z, acc0.z); acc0.w = fmaf(x0.x, w0.w, acc0.w);
      acc1.x = fmaf(x1.x, w0.x, acc1.x); acc1.y = fmaf(x1.x, w0.y, acc1.y);
      acc1.z = fmaf(x1.x, w0.z, acc1.z); acc1.w = fmaf(x1.x, w0.w, acc1.w);
      acc0.x = fmaf(x0.y, w1.x, acc0.x); acc0.y = fmaf(x0.y, w1.y, acc0.y);
      acc0.z = fmaf(x0.y, w1.z, acc0.z); acc0.w = fmaf(x0.y, w1.w, acc0.w);
      acc1.x = fmaf(x1.y, w1.x, acc1.x); acc1.y = fmaf(x1.y, w1.y, acc1.y);
      acc1.z = fmaf(x1.y, w1.z, acc1.z); acc1.w = fmaf(x1.y, w1.w, acc1.w);
      acc0.x = fmaf(x0.z, w2.x, acc0.x); acc0.y = fmaf(x0.z, w2.y, acc0.y);
      acc0.z = fmaf(x0.z, w2.z, acc0.z); acc0.w = fmaf(x0.z, w2.w, acc0.w);
      acc1.x = fmaf(x1.z, w2.x, acc1.x); acc1.y = fmaf(x1.z, w2.y, acc1.y);
      acc1.z = fmaf(x1.z, w2.z, acc1.z); acc1.w = fmaf(x1.z, w2.w, acc1.w);
      acc0.x = fmaf(x0.w, w3.x, acc0.x); acc0.y = fmaf(x0.w, w3.y, acc0.y);
      acc0.z = fmaf(x0.w, w3.z, acc0.z); acc0.w = fmaf(x0.w, w3.w, acc0.w);
      acc1.x = fmaf(x1.w, w3.x, acc1.x); acc1.y = fmaf(x1.w, w3.y, acc1.y);
      acc1.z = fmaf(x1.w, w3.z, acc1.z); acc1.w = fmaf(x1.w, w3.w, acc1.w);
    }
  }
  float* dst = (m == 0) ? aP : (m == 1 ? cP : Y);
  if (m == 0) {
    const float4 bv = *(const float4*)(b1 + tx * 4);
    acc0.x += bv.x; acc0.y += bv.y; acc0.z += bv.z; acc0.w += bv.w;
    acc1.x += bv.x; acc1.y += bv.y; acc1.z += bv.z; acc1.w += bv.w;
  }
  const int r0 = i0 + ty * 2;
  *(float4*)(dst + r0 * HH + tx * 4) = acc0;
  *(float4*)(dst + (r0 + 1) * HH + tx * 4) = acc1;
}

// ---------------------------------------------------------------------------
// K2: pairwise sim -> symmetric A (diag=1) with FUSED degree accumulation.
// grid 528 = linearized upper-triangle 32x32 tiles; block 256, 2x2 per thread.
// ---------------------------------------------------------------------------
__global__ __launch_bounds__(256) void k2_pairwise(
    const float* __restrict__ aP, const float* __restrict__ cP,
    const float* __restrict__ W2, const float* __restrict__ b2,
    float* __restrict__ A, float* __restrict__ deg) {
  __shared__ float as[32 * 132];
  __shared__ float cs[32 * 132];
  __shared__ float es[32 * 33];
  __shared__ float ws2[128];
  const int tid = threadIdx.x;
  // Linear tile id -> (ti, tj), ti <= tj.
  int tt = blockIdx.x, ti = 0;
  while (tt >= 32 - ti) { tt -= 32 - ti; ++ti; }
  const int tj = ti + tt;
  const int i0 = ti * 32, j0 = tj * 32;
  if (tid < 32) *(float4*)(ws2 + tid * 4) = *(const float4*)(W2 + tid * 4);
  for (int idx = tid; idx < 32 * HH; idx += 256) {
    const int row = idx >> 7, col = idx & 127;
    as[row * 132 + col] = aP[(i0 + row) * HH + col];
    cs[row * 132 + col] = cP[(j0 + row) * HH + col];
  }
  __syncthreads();
  const int li0 = (tid >> 4) * 2, lj0 = (tid & 15) * 2;
  float s00 = 0.f, s01 = 0.f, s10 = 0.f, s11 = 0.f;
#pragma unroll 8
  for (int h = 0; h < HH; h += 4) {
    const float4 a0 = *(const float4*)(as + li0 * 132 + h);
    const float4 a1 = *(const float4*)(as + (li0 + 1) * 132 + h);
    const float4 c0 = *(const float4*)(cs + lj0 * 132 + h);
    const float4 c1 = *(const float4*)(cs + (lj0 + 1) * 132 + h);
    const float4 w = *(const float4*)(ws2 + h);
    s00 += fmaxf(a0.x + c0.x, 0.f) * w.x + fmaxf(a0.y + c0.y, 0.f) * w.y +
           fmaxf(a0.z + c0.z, 0.f) * w.z + fmaxf(a0.w + c0.w, 0.f) * w.w;
    s01 += fmaxf(a0.x + c1.x, 0.f) * w.x + fmaxf(a0.y + c1.y, 0.f) * w.y +
           fmaxf(a0.z + c1.z, 0.f) * w.z + fmaxf(a0.w + c1.w, 0.f) * w.w;
    s10 += fmaxf(a1.x + c0.x, 0.f) * w.x + fmaxf(a1.y + c0.y, 0.f) * w.y +
           fmaxf(a1.z + c0.z, 0.f) * w.z + fmaxf(a1.w + c0.w, 0.f) * w.w;
    s11 += fmaxf(a1.x + c1.x, 0.f) * w.x + fmaxf(a1.y + c1.y, 0.f) * w.y +
           fmaxf(a1.z + c1.z, 0.f) * w.z + fmaxf(a1.w + c1.w, 0.f) * w.w;
  }
  const float b2v = b2[0];
  auto edge = [b2v](float s) {
    s += b2v;
    return s > 0.f ? 1.f / (1.f + __expf(-s)) : 0.f;  // sigmoid>0.5 <=> s>0
  };
  es[(li0 + 0) * 33 + lj0 + 0] = edge(s00);
  es[(li0 + 0) * 33 + lj0 + 1] = edge(s01);
  es[(li0 + 1) * 33 + lj0 + 0] = edge(s10);
  es[(li0 + 1) * 33 + lj0 + 1] = edge(s11);
  __syncthreads();
  if (ti == tj) {  // finalize diagonal tile: diag=1, mirror upper into lower
    float f[2][2];
#pragma unroll
    for (int r = 0; r < 2; ++r)
#pragma unroll
      for (int c = 0; c < 2; ++c) {
        const int li = li0 + r, lj = lj0 + c;
        f[r][c] =
            (li == lj) ? 1.f : (li < lj ? es[li * 33 + lj] : es[lj * 33 + li]);
      }
    __syncthreads();
    es[(li0 + 0) * 33 + lj0 + 0] = f[0][0];
    es[(li0 + 0) * 33 + lj0 + 1] = f[0][1];
    es[(li0 + 1) * 33 + lj0 + 0] = f[1][0];
    es[(li0 + 1) * 33 + lj0 + 1] = f[1][1];
    __syncthreads();
  }
  // Fused degree: row sums -> deg[i0+..]; col sums -> deg[j0+..] (off-diag).
  if (tid < 32) {
    float s = 0.f;
#pragma unroll
    for (int c = 0; c < 32; ++c) s += es[tid * 33 + c];
    atomicAdd(deg + i0 + tid, s);
  } else if (tid < 64 && ti != tj) {
    const int c = tid - 32;
    float s = 0.f;
#pragma unroll
    for (int r = 0; r < 32; ++r) s += es[r * 33 + c];
    atomicAdd(deg + j0 + c, s);
  }
  // Write A (+ mirror for off-diagonal), rows coalesced.
#pragma unroll
  for (int r = 0; r < 2; ++r)
#pragma unroll
    for (int c = 0; c < 2; ++c) {
      const int li = li0 + r, lj = lj0 + c;
      A[(i0 + li) * NN + j0 + lj] = es[li * 33 + lj];
      if (ti != tj) A[(j0 + li) * NN + i0 + lj] = es[lj * 33 + li];
    }
}

// ---------------------------------------------------------------------------
// K3: out_pre = diag(dis) A diag(dis) Y + bg, fused BN-stats atomics.
// grid 256 x 4 rows. Threads = 32 h-chunks (tx) x 8 j-slices (ty).
// A tile staged TRANSPOSED with dis[j] pre-folded: Ast[j][r] -> one broadcast
// ds_read_b128 per j. Y read as coalesced float4 (pipelined, independent).
// ---------------------------------------------------------------------------
__global__ __launch_bounds__(256) void k3_spmm(
    const float* __restrict__ A, const float* __restrict__ Y,
    const float* __restrict__ deg, const float* __restrict__ bg,
    float* __restrict__ out_pre, float* __restrict__ stats) {
  __shared__ float Ast[NN * 4];      // 16 KB: [j][r] = A[i0+r][j] * dis[j]
  __shared__ float disl[NN];         // 4 KB: rsqrt(deg)
  __shared__ float red[8 * 520];     // ~16.25 KB: [ty][r*128+h], pad 8
  __shared__ float sm1[256], sm2[256];
  const int tid = threadIdx.x;
  const int i0 = blockIdx.x * 4;
  // Phase A: dis = rsqrt(deg) into LDS.
  {
    const float4 dv = *(const float4*)(deg + tid * 4);
    float4 r;
    r.x = rsqrtf(dv.x); r.y = rsqrtf(dv.y);
    r.z = rsqrtf(dv.z); r.w = rsqrtf(dv.w);
    *(float4*)(disl + tid * 4) = r;
  }
  __syncthreads();
  // Phase B: stage A rows transposed with dis folded in.
  const float* Ab = A + i0 * NN;     // contiguous 16 KB
#pragma unroll
  for (int v = 0; v < 4; ++v) {
    const int fi = (v * 256 + tid) * 4;
    const float4 av = *(const float4*)(Ab + fi);
    const int r = fi >> 10, j = fi & 1023;
    Ast[(j + 0) * 4 + r] = av.x * disl[j + 0];
    Ast[(j + 1) * 4 + r] = av.y * disl[j + 1];
    Ast[(j + 2) * 4 + r] = av.z * disl[j + 2];
    Ast[(j + 3) * 4 + r] = av.w * disl[j + 3];
  }
  __syncthreads();
  // Phase C: main loop. acc[r] = partial of row i0+r over this j-slice.
  const int tx = tid & 31, ty = tid >> 5;
  const int jbase = ty * 128;
  float4 acc[4];
#pragma unroll
  for (int r = 0; r < 4; ++r) acc[r] = make_float4(0.f, 0.f, 0.f, 0.f);
  const float* Yb = Y + jbase * HH + tx * 4;
#pragma unroll 4
  for (int jj = 0; jj < 128; ++jj) {
    const float4 yv = *(const float4*)(Yb + jj * HH);
    const float4 ab = *(const float4*)(Ast + (jbase + jj) * 4);
    acc[0].x = fmaf(ab.x, yv.x, acc[0].x); acc[0].y = fmaf(ab.x, yv.y, acc[0].y);
    acc[0].z = fmaf(ab.x, yv.z, acc[0].z); acc[0].w = fmaf(ab.x, yv.w, acc[0].w);
    acc[1].x = fmaf(ab.y, yv.x, acc[1].x); acc[1].y = fmaf(ab.y, yv.y, acc[1].y);
    acc[1].z = fmaf(ab.y, yv.z, acc[1].z); acc[1].w = fmaf(ab.y, yv.w, acc[1].w);
    acc[2].x = fmaf(ab.z, yv.x, acc[2].x); acc[2].y = fmaf(ab.z, yv.y, acc[2].y);
    acc[2].z = fmaf(ab.z, yv.z, acc[2].z); acc[2].w = fmaf(ab.z, yv.w, acc[2].w);
    acc[3].x = fmaf(ab.w, yv.x, acc[3].x); acc[3].y = fmaf(ab.w, yv.y, acc[3].y);
    acc[3].z = fmaf(ab.w, yv.z, acc[3].z); acc[3].w = fmaf(ab.w, yv.w, acc[3].w);
  }
  // Phase D: write per-slice partials, reduce over ty.
#pragma unroll
  for (int r = 0; r < 4; ++r)
    *(float4*)(red + ty * 520 + r * 128 + tx * 4) = acc[r];
  __syncthreads();
  const int h = tid & 127, rr = tid >> 7;  // this thread: rows rr and rr+2
  float v0 = 0.f, v1 = 0.f;
#pragma unroll
  for (int t = 0; t < 8; ++t) {
    v0 += red[t * 520 + rr * 128 + h];
    v1 += red[t * 520 + (rr + 2) * 128 + h];
  }
  const float bgv = bg[h];
  v0 = v0 * disl[i0 + rr] + bgv;
  v1 = v1 * disl[i0 + rr + 2] + bgv;
  out_pre[(i0 + rr) * HH + h] = v0;
  out_pre[(i0 + rr + 2) * HH + h] = v1;
  sm1[rr * 128 + h] = v0 + v1;
  sm2[rr * 128 + h] = v0 * v0 + v1 * v1;
  __syncthreads();
  if (rr == 0) {
    atomicAdd(&stats[h], sm1[h] + sm1[128 + h]);
    atomicAdd(&stats[128 + h], sm2[h] + sm2[128 + h]);
  }
}

// ---------------------------------------------------------------------------
// K4: BatchNorm (batch stats, biased var) + ReLU -> d_out. grid 512, blk 256
// ---------------------------------------------------------------------------
__global__ __launch_bounds__(256) void k4_bn(
    const float* __restrict__ out_pre, const float* __restrict__ stats,
    const float* __restrict__ gamma, const float* __restrict__ beta,
    float* __restrict__ out) {
  const int idx = blockIdx.x * 256 + threadIdx.x;
  const int h = idx & 127;
  const float mean = stats[h] * (1.f / NN);
  const float var = stats[128 + h] * (1.f / NN) - mean * mean;
  float v = (out_pre[idx] - mean) * rsqrtf(var + BN_EPS);
  v = gamma[h] * v + beta[h];
  out[idx] = fmaxf(v, 0.f);
}

// ---------------------------------------------------------------------------
extern "C" void kernel_launch(void* const* d_in, const int* in_sizes, int n_in,
                              void* d_out, int out_size, void* d_ws,
                              size_t ws_size, hipStream_t stream) {
  const float* X = (const float*)d_in[0];
  const float* W1 = (const float*)d_in[1];
  const float* b1 = (const float*)d_in[2];
  const float* W2 = (const float*)d_in[3];
  const float* b2 = (const float*)d_in[4];
  const float* Wg = (const float*)d_in[5];
  const float* bg = (const float*)d_in[6];
  const float* gamma = (const float*)d_in[7];
  const float* beta = (const float*)d_in[8];
  float* out = (float*)d_out;

  float* w = (float*)d_ws;
  float* A = w + OFF_A;
  float* aP = w + OFF_AP;
  float* cP = w + OFF_CP;
  float* Y = w + OFF_Y;
  float* deg = w + OFF_DEG;
  float* stats = w + OFF_STATS;
  float* out_pre = w + OFF_OUTPRE;

  k1_gemm<<<dim3(194), 256, 0, stream>>>(X, W1, Wg, b1, aP, cP, Y, deg, stats);
  k2_pairwise<<<dim3(528), 256, 0, stream>>>(aP, cP, W2, b2, A, deg);
  k3_spmm<<<dim3(256), 256, 0, stream>>>(A, Y, deg, bg, out_pre, stats);
  k4_bn<<<dim3(512), 256, 0, stream>>>(out_pre, stats, gamma, beta, out);
}